// Round 5
// baseline (2193.211 us; speedup 1.0000x reference)
//
#include <hip/hip_runtime.h>

#define T_STEPS 512
#define HS 20       // hidden size
#define F0 10       // input features (layer 0)
#define BPB 3       // batches per block (20-lane groups)
#define NB_TOT 4096
#define NBLK ((NB_TOT + BPB - 1) / BPB)   // 1366

__device__ __forceinline__ float sigmoid_fast(float v) {
    return __fdividef(1.f, 1.f + __expf(-v));
}
__device__ __forceinline__ float tanh_fast(float v) {
    return 1.f - __fdividef(2.f, __expf(2.f * v) + 1.f);
}
#define PIN(v) asm volatile("" : "+v"(v))

// Block = 2 waves, 3 batches. Gate-split x layer-pipeline:
//   wave0 owns gate rows {i,f} of BOTH layers; wave1 owns {g,o}.
//   At iter t: layer0 computes step t, layer1 computes step t-1 (skew 1).
//   Per-lane weights: 2 L0 rows (K=30) + 2 L1 rows (K=40) = 140 floats ->
//   arch-VGPR resident at 3 waves/SIMD (__launch_bounds__ cap 170).
//   One h0(t-1) LDS read serves all 4 owned rows. 2 barriers/iter.
__global__ __launch_bounds__(128, 3)
void lstm2_fc_kernel(const float* __restrict__ x,
                     const float* __restrict__ wih0, const float* __restrict__ whh0,
                     const float* __restrict__ bih0, const float* __restrict__ bhh0,
                     const float* __restrict__ wih1, const float* __restrict__ whh1,
                     const float* __restrict__ bih1, const float* __restrict__ bhh1,
                     const float* __restrict__ wfc,  const float* __restrict__ bfc,
                     float* __restrict__ out)
{
    const int tid  = threadIdx.x;
    const int wid  = tid >> 6;          // 0: gates {i,f}; 1: gates {g,o}
    const int lane = tid & 63;
    const int g    = (lane / HS) % BPB; // batch slot; lanes 60..63 shadow slot 0
    const int u    = lane % HS;
    const int bg   = blockIdx.x * BPB + g;
    const int bgc  = (bg < NB_TOT) ? bg : (NB_TOT - 1);

    __shared__ float s_h0[2][BPB][HS];    // double-buffered h0
    __shared__ float s_h1[BPB][HS];       // h1 (single buffer, phase-separated)
    __shared__ float s_preA[2][BPB][HS];  // layer0 {g,o} preacts: wave1 -> wave0
    __shared__ float s_preB[2][BPB][HS];  // layer1 {i,f} preacts: wave0 -> wave1

    for (int i = tid; i < 2 * BPB * HS; i += 128) (&s_h0[0][0][0])[i] = 0.f;
    for (int i = tid; i < BPB * HS; i += 128)     (&s_h1[0][0])[i]    = 0.f;

    // ---- per-lane register weights: rows (2*wid)*HS+u and (2*wid+1)*HS+u ----
    float wx[2][F0], wh[2][HS], v0[2][HS], v1[2][HS], ba[2], bb[2];
    #pragma unroll
    for (int q = 0; q < 2; ++q) {
        const int r = (2 * wid + q) * HS + u;
        #pragma unroll
        for (int f = 0; f < F0; ++f) { wx[q][f] = wih0[r * F0 + f]; PIN(wx[q][f]); }
        #pragma unroll
        for (int j = 0; j < HS; ++j) { wh[q][j] = whh0[r * HS + j]; PIN(wh[q][j]); }
        #pragma unroll
        for (int j = 0; j < HS; ++j) { v0[q][j] = wih1[r * HS + j]; PIN(v0[q][j]); }
        #pragma unroll
        for (int j = 0; j < HS; ++j) { v1[q][j] = whh1[r * HS + j]; PIN(v1[q][j]); }
        ba[q] = bih0[r] + bhh0[r]; PIN(ba[q]);
        bb[q] = bih1[r] + bhh1[r]; PIN(bb[q]);
    }

    float c = 0.f;   // c0 for wave0 lanes, c1 for wave1 lanes
    const float* xb = x + (size_t)bgc * (T_STEPS * F0);

    __syncthreads();

    for (int t = 0; t <= T_STEPS; ++t) {
        // ---------- phase 1: gate pre-activations ----------
        float xr[F0];
        {
            const int tx = (t < T_STEPS) ? t : (T_STEPS - 1);  // clamp (unused at t=T)
            const float2* p = (const float2*)(xb + tx * F0);
            #pragma unroll
            for (int f = 0; f < F0 / 2; ++f) {
                float2 v = p[f];
                xr[2 * f] = v.x; xr[2 * f + 1] = v.y;
            }
        }
        float a0 = ba[0], a1 = ba[1];   // layer0 owned rows (step t)
        float d0 = bb[0], d1 = bb[1];   // layer1 owned rows (step t-1)
        #pragma unroll
        for (int f = 0; f < F0; ++f) {
            a0 = fmaf(xr[f], wx[0][f], a0);
            a1 = fmaf(xr[f], wx[1][f], a1);
        }
        const float* h0p = &s_h0[(t + 1) & 1][g][0];   // h0(t-1)
        #pragma unroll
        for (int q4 = 0; q4 < HS / 4; ++q4) {
            const float4 h4 = *(const float4*)(h0p + 4 * q4);
            const float e[4] = {h4.x, h4.y, h4.z, h4.w};
            #pragma unroll
            for (int s = 0; s < 4; ++s) {
                const int k = 4 * q4 + s;
                a0 = fmaf(e[s], wh[0][k], a0);   // layer0 <- h0(t-1)
                a1 = fmaf(e[s], wh[1][k], a1);
                d0 = fmaf(e[s], v0[0][k], d0);   // layer1 <- h0(t-1) (same vector!)
                d1 = fmaf(e[s], v0[1][k], d1);
            }
        }
        const float* h1p = &s_h1[g][0];                // h1(t-2)
        #pragma unroll
        for (int q4 = 0; q4 < HS / 4; ++q4) {
            const float4 h4 = *(const float4*)(h1p + 4 * q4);
            const float e[4] = {h4.x, h4.y, h4.z, h4.w};
            #pragma unroll
            for (int s = 0; s < 4; ++s) {
                const int k = 4 * q4 + s;
                d0 = fmaf(e[s], v1[0][k], d0);   // layer1 <- h1(t-2)
                d1 = fmaf(e[s], v1[1][k], d1);
            }
        }
        if (wid == 0) {        // publish layer1 {i,f}
            s_preB[0][g][u] = d0;
            s_preB[1][g][u] = d1;
        } else {               // publish layer0 {g,o}
            s_preA[0][g][u] = a0;
            s_preA[1][g][u] = a1;
        }
        __syncthreads();

        // ---------- phase 2: state updates ----------
        if (wid == 0) {
            if (t < T_STEPS) {                 // layer0 step t
                const float ii = sigmoid_fast(a0);
                const float ff = sigmoid_fast(a1);
                const float gg = tanh_fast(s_preA[0][g][u]);
                const float oo = sigmoid_fast(s_preA[1][g][u]);
                c = ff * c + ii * gg;
                s_h0[t & 1][g][u] = oo * tanh_fast(c);
            }
        } else {
            if (t >= 1) {                      // layer1 step t-1
                const float ii = sigmoid_fast(s_preB[0][g][u]);
                const float ff = sigmoid_fast(s_preB[1][g][u]);
                const float gg = tanh_fast(d0);
                const float oo = sigmoid_fast(d1);
                c = ff * c + ii * gg;
                s_h1[g][u] = oo * tanh_fast(c);
            }
        }
        __syncthreads();
    }

    // ---- final FC on h1(T-1) ----
    if (wid == 1 && lane < BPB * HS && u == 0 && bg < NB_TOT) {
        float o = bfc[0];
        #pragma unroll
        for (int j = 0; j < HS; ++j) o = fmaf(s_h1[g][j], wfc[j], o);
        out[bg] = o;
    }
}

extern "C" void kernel_launch(void* const* d_in, const int* in_sizes, int n_in,
                              void* d_out, int out_size, void* d_ws, size_t ws_size,
                              hipStream_t stream) {
    const float* x    = (const float*)d_in[0];
    const float* wih0 = (const float*)d_in[1];
    const float* whh0 = (const float*)d_in[2];
    const float* bih0 = (const float*)d_in[3];
    const float* bhh0 = (const float*)d_in[4];
    const float* wih1 = (const float*)d_in[5];
    const float* whh1 = (const float*)d_in[6];
    const float* bih1 = (const float*)d_in[7];
    const float* bhh1 = (const float*)d_in[8];
    const float* wfc  = (const float*)d_in[9];
    const float* bfc  = (const float*)d_in[10];
    float* out = (float*)d_out;

    dim3 grid(NBLK), block(128);
    hipLaunchKernelGGL(lstm2_fc_kernel, grid, block, 0, stream,
                       x, wih0, whh0, bih0, bhh0,
                       wih1, whh1, bih1, bhh1, wfc, bfc, out);
}

// Round 6
// 2022.368 us; speedup vs baseline: 1.0845x; 1.0845x over previous
//
#include <hip/hip_runtime.h>

#define T_STEPS 512
#define HS 20       // hidden size
#define F0 10       // input features (layer 0)
#define BPB 3       // batches per block (20-lane groups)
#define NB_TOT 4096
#define NBLK ((NB_TOT + BPB - 1) / BPB)   // 1366
#define V1PAD 22    // whh1 LDS row stride: 22 floats = 88 B, 8B-aligned, <=2-way banks

__device__ __forceinline__ float sigmoid_fast(float v) {
    return __fdividef(1.f, 1.f + __expf(-v));
}
__device__ __forceinline__ float tanh_fast(float v) {
    return 1.f - __fdividef(2.f, __expf(2.f * v) + 1.f);
}
#define PIN(v) asm volatile("" : "+v"(v))

// Block = 2 waves, 3 batches. Gate-split x layer-pipeline (R5 structure):
//   wave0 owns gate rows {i,f} of BOTH layers; wave1 owns {g,o}.
//   At iter t: layer0 computes step t, layer1 computes step t-1 (skew 1).
// R6 change: whh1 (40 floats/lane) lives in LDS, not registers ->
//   per-lane register weights = 104 (+4 bias), total live ~145 < 170 budget
//   of __launch_bounds__(128,3) -> 3 waves/SIMD, 2732 waves in ONE round.
__global__ __launch_bounds__(128, 3)
void lstm2_fc_kernel(const float* __restrict__ x,
                     const float* __restrict__ wih0, const float* __restrict__ whh0,
                     const float* __restrict__ bih0, const float* __restrict__ bhh0,
                     const float* __restrict__ wih1, const float* __restrict__ whh1,
                     const float* __restrict__ bih1, const float* __restrict__ bhh1,
                     const float* __restrict__ wfc,  const float* __restrict__ bfc,
                     float* __restrict__ out)
{
    const int tid  = threadIdx.x;
    const int wid  = tid >> 6;          // 0: gates {i,f}; 1: gates {g,o}
    const int lane = tid & 63;
    const int g    = (lane / HS) % BPB; // batch slot; lanes 60..63 shadow slot 0
    const int u    = lane % HS;
    const int bg   = blockIdx.x * BPB + g;
    const int bgc  = (bg < NB_TOT) ? bg : (NB_TOT - 1);

    __shared__ float s_h0[2][BPB][HS];    // double-buffered h0
    __shared__ float s_h1[BPB][HS];       // h1 (single buffer, phase-separated)
    __shared__ float s_preA[2][BPB][HS];  // layer0 {g,o} preacts: wave1 -> wave0
    __shared__ float s_preB[2][BPB][HS];  // layer1 {i,f} preacts: wave0 -> wave1
    __shared__ float s_v1[4 * HS][V1PAD]; // whh1 rows (padded)

    for (int i = tid; i < 2 * BPB * HS; i += 128) (&s_h0[0][0][0])[i] = 0.f;
    for (int i = tid; i < BPB * HS; i += 128)     (&s_h1[0][0])[i]    = 0.f;
    for (int i = tid; i < 4 * HS * HS; i += 128) {
        const int r = i / HS, k = i % HS;
        s_v1[r][k] = whh1[i];
    }

    // ---- per-lane register weights: rows (2*wid)*HS+u and (2*wid+1)*HS+u ----
    float wx[2][F0], wh[2][HS], v0[2][HS], ba[2], bb[2];
    #pragma unroll
    for (int q = 0; q < 2; ++q) {
        const int r = (2 * wid + q) * HS + u;
        #pragma unroll
        for (int f = 0; f < F0; ++f) { wx[q][f] = wih0[r * F0 + f]; PIN(wx[q][f]); }
        #pragma unroll
        for (int j = 0; j < HS; ++j) { wh[q][j] = whh0[r * HS + j]; PIN(wh[q][j]); }
        #pragma unroll
        for (int j = 0; j < HS; ++j) { v0[q][j] = wih1[r * HS + j]; PIN(v0[q][j]); }
        ba[q] = bih0[r] + bhh0[r]; PIN(ba[q]);
        bb[q] = bih1[r] + bhh1[r]; PIN(bb[q]);
    }

    const float* v1p0 = &s_v1[(2 * wid + 0) * HS + u][0];
    const float* v1p1 = &s_v1[(2 * wid + 1) * HS + u][0];

    float c = 0.f;   // c0 for wave0 lanes, c1 for wave1 lanes
    const float* xb = x + (size_t)bgc * (T_STEPS * F0);

    __syncthreads();

    for (int t = 0; t <= T_STEPS; ++t) {
        // ---------- phase 1: gate pre-activations ----------
        float a0 = ba[0], a1 = ba[1];   // layer0 owned rows (step t)
        float d0 = bb[0], d1 = bb[1];   // layer1 owned rows (step t-1)
        {
            const int tx = (t < T_STEPS) ? t : (T_STEPS - 1);  // clamp (unused at t=T)
            const float2* p = (const float2*)(xb + tx * F0);
            #pragma unroll
            for (int f2 = 0; f2 < F0 / 2; ++f2) {
                const float2 v = p[f2];
                a0 = fmaf(v.x, wx[0][2 * f2], a0);
                a1 = fmaf(v.x, wx[1][2 * f2], a1);
                a0 = fmaf(v.y, wx[0][2 * f2 + 1], a0);
                a1 = fmaf(v.y, wx[1][2 * f2 + 1], a1);
            }
        }
        const float* h0p = &s_h0[(t + 1) & 1][g][0];   // h0(t-1)
        #pragma unroll
        for (int q4 = 0; q4 < HS / 4; ++q4) {
            const float4 h4 = *(const float4*)(h0p + 4 * q4);
            const int k = 4 * q4;
            a0 = fmaf(h4.x, wh[0][k],     a0);  a1 = fmaf(h4.x, wh[1][k],     a1);
            d0 = fmaf(h4.x, v0[0][k],     d0);  d1 = fmaf(h4.x, v0[1][k],     d1);
            a0 = fmaf(h4.y, wh[0][k + 1], a0);  a1 = fmaf(h4.y, wh[1][k + 1], a1);
            d0 = fmaf(h4.y, v0[0][k + 1], d0);  d1 = fmaf(h4.y, v0[1][k + 1], d1);
            a0 = fmaf(h4.z, wh[0][k + 2], a0);  a1 = fmaf(h4.z, wh[1][k + 2], a1);
            d0 = fmaf(h4.z, v0[0][k + 2], d0);  d1 = fmaf(h4.z, v0[1][k + 2], d1);
            a0 = fmaf(h4.w, wh[0][k + 3], a0);  a1 = fmaf(h4.w, wh[1][k + 3], a1);
            d0 = fmaf(h4.w, v0[0][k + 3], d0);  d1 = fmaf(h4.w, v0[1][k + 3], d1);
        }
        const float* h1p = &s_h1[g][0];                // h1(t-2)
        #pragma unroll
        for (int q4 = 0; q4 < HS / 4; ++q4) {
            const float4 h4  = *(const float4*)(h1p + 4 * q4);
            const float2 wa0 = *(const float2*)(v1p0 + 4 * q4);
            const float2 wb0 = *(const float2*)(v1p0 + 4 * q4 + 2);
            const float2 wa1 = *(const float2*)(v1p1 + 4 * q4);
            const float2 wb1 = *(const float2*)(v1p1 + 4 * q4 + 2);
            d0 = fmaf(h4.x, wa0.x, d0);  d1 = fmaf(h4.x, wa1.x, d1);
            d0 = fmaf(h4.y, wa0.y, d0);  d1 = fmaf(h4.y, wa1.y, d1);
            d0 = fmaf(h4.z, wb0.x, d0);  d1 = fmaf(h4.z, wb1.x, d1);
            d0 = fmaf(h4.w, wb0.y, d0);  d1 = fmaf(h4.w, wb1.y, d1);
            if (q4 == 2) __builtin_amdgcn_sched_barrier(0);  // cap load hoisting
        }
        if (wid == 0) {        // publish layer1 {i,f}
            s_preB[0][g][u] = d0;
            s_preB[1][g][u] = d1;
        } else {               // publish layer0 {g,o}
            s_preA[0][g][u] = a0;
            s_preA[1][g][u] = a1;
        }
        __syncthreads();

        // ---------- phase 2: state updates ----------
        if (wid == 0) {
            if (t < T_STEPS) {                 // layer0 step t
                const float ii = sigmoid_fast(a0);
                const float ff = sigmoid_fast(a1);
                const float gg = tanh_fast(s_preA[0][g][u]);
                const float oo = sigmoid_fast(s_preA[1][g][u]);
                c = ff * c + ii * gg;
                s_h0[t & 1][g][u] = oo * tanh_fast(c);
            }
        } else {
            if (t >= 1) {                      // layer1 step t-1
                const float ii = sigmoid_fast(s_preB[0][g][u]);
                const float ff = sigmoid_fast(s_preB[1][g][u]);
                const float gg = tanh_fast(d0);
                const float oo = sigmoid_fast(d1);
                c = ff * c + ii * gg;
                s_h1[g][u] = oo * tanh_fast(c);
            }
        }
        __syncthreads();
    }

    // ---- final FC on h1(T-1) ----
    if (wid == 1 && lane < BPB * HS && u == 0 && bg < NB_TOT) {
        float o = bfc[0];
        #pragma unroll
        for (int j = 0; j < HS; ++j) o = fmaf(s_h1[g][j], wfc[j], o);
        out[bg] = o;
    }
}

extern "C" void kernel_launch(void* const* d_in, const int* in_sizes, int n_in,
                              void* d_out, int out_size, void* d_ws, size_t ws_size,
                              hipStream_t stream) {
    const float* x    = (const float*)d_in[0];
    const float* wih0 = (const float*)d_in[1];
    const float* whh0 = (const float*)d_in[2];
    const float* bih0 = (const float*)d_in[3];
    const float* bhh0 = (const float*)d_in[4];
    const float* wih1 = (const float*)d_in[5];
    const float* whh1 = (const float*)d_in[6];
    const float* bih1 = (const float*)d_in[7];
    const float* bhh1 = (const float*)d_in[8];
    const float* wfc  = (const float*)d_in[9];
    const float* bfc  = (const float*)d_in[10];
    float* out = (float*)d_out;

    dim3 grid(NBLK), block(128);
    hipLaunchKernelGGL(lstm2_fc_kernel, grid, block, 0, stream,
                       x, wih0, whh0, bih0, bhh0,
                       wih1, whh1, bih1, bhh1, wfc, bfc, out);
}

// Round 7
// 916.915 us; speedup vs baseline: 2.3919x; 2.2056x over previous
//
#include <hip/hip_runtime.h>

#define T_STEPS 512
#define HS 20       // hidden size
#define F0 10       // input features (layer 0)
#define BPB 6       // batches per block: lane-group g handles batches {g, g+3}
#define NB_TOT 4096
#define NBLK ((NB_TOT + BPB - 1) / BPB)   // 683

__device__ __forceinline__ float sigmoid_fast(float v) {
    return __fdividef(1.f, 1.f + __expf(-v));
}
__device__ __forceinline__ float tanh_fast(float v) {
    return 1.f - __fdividef(2.f, __expf(2.f * v) + 1.f);
}
#define PIN(v) asm volatile("" : "+v"(v))

// R4 structure (the only proven spill-free config) + 2 batches/lane:
//   wave0: layer0 for 6 batches; wave1: layer1 for 6 batches, skewed 1 step.
//   Shared w[4][40] per lane (union of both roles) -> 164 live floats at
//   (128,2) budget 256: arch VGPRs + AGPR overflow, NO scratch (R4-verified).
//   683 blocks = 1366 waves <= 2048 capacity -> ONE dispatch round.
__global__ __launch_bounds__(128, 2)
void lstm2_fc_kernel(const float* __restrict__ x,
                     const float* __restrict__ wih0, const float* __restrict__ whh0,
                     const float* __restrict__ bih0, const float* __restrict__ bhh0,
                     const float* __restrict__ wih1, const float* __restrict__ whh1,
                     const float* __restrict__ bih1, const float* __restrict__ bhh1,
                     const float* __restrict__ wfc,  const float* __restrict__ bfc,
                     float* __restrict__ out)
{
    const int tid  = threadIdx.x;
    const int wid  = tid >> 6;
    const int lane = tid & 63;
    const int g    = (lane / HS) % 3;   // lanes 60..63 shadow group 0 (benign dups)
    const int u    = lane % HS;
    const int bgA  = blockIdx.x * BPB + g;          // < 4096 always (682*6+2=4094)
    const int bgBr = blockIdx.x * BPB + g + 3;
    const bool okB = (bgBr < NB_TOT);
    const int bgB  = okB ? bgBr : (NB_TOT - 1);     // clamp reads

    __shared__ float s_h0[2][BPB][HS];   // double buffer: wave0 -> wave1
    __shared__ float s_h1[BPB][HS];      // wave1-private recurrence state

    for (int i = tid; i < 2 * BPB * HS; i += 128) (&s_h0[0][0][0])[i] = 0.f;
    for (int i = tid; i < BPB * HS; i += 128)     (&s_h1[0][0])[i]    = 0.f;

    // ---- per-lane weights, SHARED storage between the two wave roles ----
    // wave0: w[q][0..9] = wih0 row, w[q][10..29] = whh0 row, 30..39 unused
    // wave1: w[q][0..19] = wih1 row, w[q][20..39] = whh1 row
    float w[4][2 * HS], bias[4];
    if (wid == 0) {
        #pragma unroll
        for (int q = 0; q < 4; ++q) {
            const int row = q * HS + u;
            #pragma unroll
            for (int f = 0; f < F0; ++f) { w[q][f] = wih0[row * F0 + f]; PIN(w[q][f]); }
            #pragma unroll
            for (int j = 0; j < HS; ++j) { w[q][F0 + j] = whh0[row * HS + j]; PIN(w[q][F0 + j]); }
            bias[q] = bih0[row] + bhh0[row]; PIN(bias[q]);
        }
    } else {
        #pragma unroll
        for (int q = 0; q < 4; ++q) {
            const int row = q * HS + u;
            #pragma unroll
            for (int j = 0; j < HS; ++j) { w[q][j]      = wih1[row * HS + j]; PIN(w[q][j]); }
            #pragma unroll
            for (int j = 0; j < HS; ++j) { w[q][HS + j] = whh1[row * HS + j]; PIN(w[q][HS + j]); }
            bias[q] = bih1[row] + bhh1[row]; PIN(bias[q]);
        }
    }

    float cA = 0.f, cB = 0.f;            // c0 (wave0) / c1 (wave1) for the 2 batches
    const float* xbA = x + (size_t)bgA * (T_STEPS * F0);
    const float* xbB = x + (size_t)bgB * (T_STEPS * F0);

    __syncthreads();

    for (int t = 0; t <= T_STEPS; ++t) {
        if (wid == 0) {
            if (t < T_STEPS) {
                // x(t) loads issued first; latency overlaps the h0-FMA block
                float xA[F0], xB[F0];
                {
                    const float2* pA = (const float2*)(xbA + t * F0);
                    const float2* pB = (const float2*)(xbB + t * F0);
                    #pragma unroll
                    for (int f = 0; f < F0 / 2; ++f) {
                        float2 vA = pA[f], vB = pB[f];
                        xA[2*f] = vA.x; xA[2*f+1] = vA.y;
                        xB[2*f] = vB.x; xB[2*f+1] = vB.y;
                    }
                }
                float aA0 = bias[0], aA1 = bias[1], aA2 = bias[2], aA3 = bias[3];
                float aB0 = bias[0], aB1 = bias[1], aB2 = bias[2], aB3 = bias[3];
                const float* hpA = &s_h0[(t + 1) & 1][g][0];       // h0(t-1)
                const float* hpB = &s_h0[(t + 1) & 1][g + 3][0];
                #pragma unroll
                for (int q4 = 0; q4 < HS / 4; ++q4) {
                    const float4 hA = *(const float4*)(hpA + 4 * q4);
                    const float4 hB = *(const float4*)(hpB + 4 * q4);
                    const float eA[4] = {hA.x, hA.y, hA.z, hA.w};
                    const float eB[4] = {hB.x, hB.y, hB.z, hB.w};
                    #pragma unroll
                    for (int s = 0; s < 4; ++s) {
                        const int k = F0 + 4 * q4 + s;
                        aA0 = fmaf(eA[s], w[0][k], aA0);  aB0 = fmaf(eB[s], w[0][k], aB0);
                        aA1 = fmaf(eA[s], w[1][k], aA1);  aB1 = fmaf(eB[s], w[1][k], aB1);
                        aA2 = fmaf(eA[s], w[2][k], aA2);  aB2 = fmaf(eB[s], w[2][k], aB2);
                        aA3 = fmaf(eA[s], w[3][k], aA3);  aB3 = fmaf(eB[s], w[3][k], aB3);
                    }
                }
                #pragma unroll
                for (int f = 0; f < F0; ++f) {
                    aA0 = fmaf(xA[f], w[0][f], aA0);  aB0 = fmaf(xB[f], w[0][f], aB0);
                    aA1 = fmaf(xA[f], w[1][f], aA1);  aB1 = fmaf(xB[f], w[1][f], aB1);
                    aA2 = fmaf(xA[f], w[2][f], aA2);  aB2 = fmaf(xB[f], w[2][f], aB2);
                    aA3 = fmaf(xA[f], w[3][f], aA3);  aB3 = fmaf(xB[f], w[3][f], aB3);
                }
                {
                    const float iA = sigmoid_fast(aA0), fA = sigmoid_fast(aA1);
                    const float gA = tanh_fast(aA2),    oA = sigmoid_fast(aA3);
                    cA = fA * cA + iA * gA;
                    s_h0[t & 1][g][u] = oA * tanh_fast(cA);
                    const float iB = sigmoid_fast(aB0), fB = sigmoid_fast(aB1);
                    const float fgB = tanh_fast(aB2),   oB = sigmoid_fast(aB3);
                    cB = fB * cB + iB * fgB;
                    s_h0[t & 1][g + 3][u] = oB * tanh_fast(cB);
                }
            }
        } else {
            if (t >= 1) {
                // layer1 computes step s = t-1
                float aA0 = bias[0], aA1 = bias[1], aA2 = bias[2], aA3 = bias[3];
                float aB0 = bias[0], aB1 = bias[1], aB2 = bias[2], aB3 = bias[3];
                const float* hpA = &s_h0[(t - 1) & 1][g][0];       // h0(s)
                const float* hpB = &s_h0[(t - 1) & 1][g + 3][0];
                #pragma unroll
                for (int q4 = 0; q4 < HS / 4; ++q4) {
                    const float4 hA = *(const float4*)(hpA + 4 * q4);
                    const float4 hB = *(const float4*)(hpB + 4 * q4);
                    const float eA[4] = {hA.x, hA.y, hA.z, hA.w};
                    const float eB[4] = {hB.x, hB.y, hB.z, hB.w};
                    #pragma unroll
                    for (int s = 0; s < 4; ++s) {
                        const int k = 4 * q4 + s;
                        aA0 = fmaf(eA[s], w[0][k], aA0);  aB0 = fmaf(eB[s], w[0][k], aB0);
                        aA1 = fmaf(eA[s], w[1][k], aA1);  aB1 = fmaf(eB[s], w[1][k], aB1);
                        aA2 = fmaf(eA[s], w[2][k], aA2);  aB2 = fmaf(eB[s], w[2][k], aB2);
                        aA3 = fmaf(eA[s], w[3][k], aA3);  aB3 = fmaf(eB[s], w[3][k], aB3);
                    }
                }
                const float* ppA = &s_h1[g][0];                    // h1(s-1)
                const float* ppB = &s_h1[g + 3][0];
                #pragma unroll
                for (int q4 = 0; q4 < HS / 4; ++q4) {
                    const float4 hA = *(const float4*)(ppA + 4 * q4);
                    const float4 hB = *(const float4*)(ppB + 4 * q4);
                    const float eA[4] = {hA.x, hA.y, hA.z, hA.w};
                    const float eB[4] = {hB.x, hB.y, hB.z, hB.w};
                    #pragma unroll
                    for (int s = 0; s < 4; ++s) {
                        const int k = HS + 4 * q4 + s;
                        aA0 = fmaf(eA[s], w[0][k], aA0);  aB0 = fmaf(eB[s], w[0][k], aB0);
                        aA1 = fmaf(eA[s], w[1][k], aA1);  aB1 = fmaf(eB[s], w[1][k], aB1);
                        aA2 = fmaf(eA[s], w[2][k], aA2);  aB2 = fmaf(eB[s], w[2][k], aB2);
                        aA3 = fmaf(eA[s], w[3][k], aA3);  aB3 = fmaf(eB[s], w[3][k], aB3);
                    }
                }
                const float iA = sigmoid_fast(aA0), fA = sigmoid_fast(aA1);
                const float gA = tanh_fast(aA2),    oA = sigmoid_fast(aA3);
                const float iB = sigmoid_fast(aB0), fB = sigmoid_fast(aB1);
                const float gB = tanh_fast(aB2),    oB = sigmoid_fast(aB3);
                cA = fA * cA + iA * gA;
                cB = fB * cB + iB * gB;
                __builtin_amdgcn_wave_barrier();   // h1(s-1) reads precede writes
                s_h1[g][u]     = oA * tanh_fast(cA);
                s_h1[g + 3][u] = oB * tanh_fast(cB);
            }
        }
        __syncthreads();   // publish s_h0[t&1]; WAR-protect buffer reuse
    }

    // ---- final FC on h1(T-1) ----
    if (wid == 1 && lane < 60 && u == 0) {
        float oA = bfc[0], oB = bfc[0];
        #pragma unroll
        for (int j = 0; j < HS; ++j) {
            oA = fmaf(s_h1[g][j],     wfc[j], oA);
            oB = fmaf(s_h1[g + 3][j], wfc[j], oB);
        }
        out[bgA] = oA;
        if (okB) out[bgBr] = oB;
    }
}

extern "C" void kernel_launch(void* const* d_in, const int* in_sizes, int n_in,
                              void* d_out, int out_size, void* d_ws, size_t ws_size,
                              hipStream_t stream) {
    const float* x    = (const float*)d_in[0];
    const float* wih0 = (const float*)d_in[1];
    const float* whh0 = (const float*)d_in[2];
    const float* bih0 = (const float*)d_in[3];
    const float* bhh0 = (const float*)d_in[4];
    const float* wih1 = (const float*)d_in[5];
    const float* whh1 = (const float*)d_in[6];
    const float* bih1 = (const float*)d_in[7];
    const float* bhh1 = (const float*)d_in[8];
    const float* wfc  = (const float*)d_in[9];
    const float* bfc  = (const float*)d_in[10];
    float* out = (float*)d_out;

    dim3 grid(NBLK), block(128);
    hipLaunchKernelGGL(lstm2_fc_kernel, grid, block, 0, stream,
                       x, wih0, whh0, bih0, bhh0,
                       wih1, whh1, bih1, bhh1, wfc, bfc, out);
}